// Round 10
// baseline (22.517 us; speedup 1.0000x reference)
//
#include <hip/hip_runtime.h>

#define N 512
#define D 128

// ws layout (doubles): rs[2jh][2m][512] (8 KB) | ss[2jh][2m][512] (8 KB)
// Plain stores only — no atomics, no counters (R8's proven structure).

__device__ __forceinline__ double wave_reduce_add(double v) {
    #pragma unroll
    for (int off = 32; off > 0; off >>= 1)
        v += __shfl_down(v, off, 64);
    return v;
}

// K1: 256 blocks x 512 threads. b -> m = b>>7, ioct = (b&127)>>1, jh = b&1.
// Block computes dist(i, j) for i in [8*ioct, +8), j in [256*jh, +256).
// One LDS stage (128 KB transposed+swizzled tile), one barrier, then an
// LDS-read-minimal compute: thread = (j, d-half), 8 i-rows -> 8 FMAs per
// LDS float, 64 ds_read_b32 per thread.
// R9 bug fixed: stage loop now covers all 8192 float4 (16 passes, not 8).
__global__ __launch_bounds__(512) void gw_dist(
    const float* __restrict__ src, const float* __restrict__ tgt,
    double* __restrict__ rs, double* __restrict__ ss)
{
    __shared__ float  tile[D * 256];    // 128 KB: tile[d*256 + (j ^ ((d>>2)&31))]
    __shared__ float  part[256][9];     // hi-d-half partials (padded: no conflicts)
    __shared__ double red[8][16];       // [wave][quantity]

    const int b    = blockIdx.x;
    const int m    = b >> 7;
    const int ioct = (b & 127) >> 1;
    const int jh   = b & 1;
    const int t    = threadIdx.x;
    const int jl   = t & 255;           // local j
    const int dh   = t >> 8;            // d-half: 0 -> [0,64), 1 -> [64,128)
    const int i0   = ioct * 8;
    const int j0   = jh * 256;

    const float*  X  = m ? tgt : src;
    const float4* X4 = reinterpret_cast<const float4*>(X + j0 * D);

    // ---- stage: 256 j-rows x 32 float4 = 8192 float4, coalesced reads;
    // transposed swizzled writes X[j0+jr][4s+k] -> tile[(4s+k)*256 + (jr^s)].
    // Write banks per 32-lane group: jr uniform, s=lane -> (jr^s) permutation
    // of 0..31 -> conflict-free.
    #pragma unroll
    for (int p = 0; p < 16; ++p) {
        int f  = t + p * 512;           // flat float4 index 0..8191
        int jr = f >> 5;                // 0..255
        int s  = f & 31;
        float4 v = X4[f];
        int col = jr ^ s;
        // col = (jr & ~31) | ((jr ^ s) & 31): jr^s only permutes low 5 bits
        col = (jr & ~31) | ((jr ^ s) & 31);
        tile[(4 * s + 0) * 256 + col] = v.x;
        tile[(4 * s + 1) * 256 + col] = v.y;
        tile[(4 * s + 2) * 256 + col] = v.z;
        tile[(4 * s + 3) * 256 + col] = v.w;
    }
    __syncthreads();

    // ---- compute: 64 dims for this thread's (j, d-half), against 8 i-rows
    // (wave-uniform addresses -> scalar loads from K$).
    const int dbase = dh * 64;
    float a0 = 0.f, a1 = 0.f, a2 = 0.f, a3 = 0.f;
    float a4 = 0.f, a5 = 0.f, a6 = 0.f, a7 = 0.f;
    const float* r0 = X + (i0 + 0) * D + dbase;
    const float* r1 = X + (i0 + 1) * D + dbase;
    const float* r2 = X + (i0 + 2) * D + dbase;
    const float* r3 = X + (i0 + 3) * D + dbase;
    const float* r4 = X + (i0 + 4) * D + dbase;
    const float* r5 = X + (i0 + 5) * D + dbase;
    const float* r6 = X + (i0 + 6) * D + dbase;
    const float* r7 = X + (i0 + 7) * D + dbase;

    #pragma unroll 4
    for (int dd = 0; dd < 64; ++dd) {
        int d = dbase + dd;
        int col = (jl & ~31) | ((jl ^ (d >> 2)) & 31);
        float v = tile[d * 256 + col];  // 2 lanes/bank: free
        float e;
        e = r0[dd] - v; a0 += e * e;
        e = r1[dd] - v; a1 += e * e;
        e = r2[dd] - v; a2 += e * e;
        e = r3[dd] - v; a3 += e * e;
        e = r4[dd] - v; a4 += e * e;
        e = r5[dd] - v; a5 += e * e;
        e = r6[dd] - v; a6 += e * e;
        e = r7[dd] - v; a7 += e * e;
    }

    // ---- recombine d-halves per (i, j) BEFORE squaring ----
    if (dh == 1) {
        part[jl][0] = a0; part[jl][1] = a1; part[jl][2] = a2; part[jl][3] = a3;
        part[jl][4] = a4; part[jl][5] = a5; part[jl][6] = a6; part[jl][7] = a7;
    }
    __syncthreads();

    double q[16];
    if (dh == 0) {
        float c;
        c = a0 + part[jl][0]; q[0] = (double)c; q[8]  = (double)c * (double)c;
        c = a1 + part[jl][1]; q[1] = (double)c; q[9]  = (double)c * (double)c;
        c = a2 + part[jl][2]; q[2] = (double)c; q[10] = (double)c * (double)c;
        c = a3 + part[jl][3]; q[3] = (double)c; q[11] = (double)c * (double)c;
        c = a4 + part[jl][4]; q[4] = (double)c; q[12] = (double)c * (double)c;
        c = a5 + part[jl][5]; q[5] = (double)c; q[13] = (double)c * (double)c;
        c = a6 + part[jl][6]; q[6] = (double)c; q[14] = (double)c * (double)c;
        c = a7 + part[jl][7]; q[7] = (double)c; q[15] = (double)c * (double)c;
    } else {
        #pragma unroll
        for (int k = 0; k < 16; ++k) q[k] = 0.0;
    }

    // ---- block reduce 16 doubles (rs x8 rows, ss x8 rows) ----
    const int wave = t >> 6;
    const int lane = t & 63;
    #pragma unroll
    for (int k = 0; k < 16; ++k) {
        double v = wave_reduce_add(q[k]);
        if (lane == 0) red[wave][k] = v;
    }
    __syncthreads();

    if (t == 0) {
        const int base = ((jh << 1) | m) * N + i0;   // [jh][m][i] partials
        #pragma unroll
        for (int k = 0; k < 8; ++k) {
            double rsk = 0.0, ssk = 0.0;
            #pragma unroll
            for (int w = 0; w < 8; ++w) { rsk += red[w][k]; ssk += red[w][k + 8]; }
            rs[base + k] = rsk;   // plain stores; visible to K2 at kernel boundary
            ss[base + k] = ssk;
        }
    }
}

// K2: single block combines the 2 j-half partials and finalizes.
__global__ __launch_bounds__(512) void gw_finalize(
    const double* __restrict__ rs, const double* __restrict__ ss,
    float* __restrict__ out)
{
    const int i = threadIdx.x;

    // index ((jh<<1)|m)*N + i
    const double rs_s = rs[0 * N + i] + rs[2 * N + i];
    const double rs_t = rs[1 * N + i] + rs[3 * N + i];
    const double ss_s = ss[0 * N + i] + ss[2 * N + i];
    const double ss_t = ss[1 * N + i] + ss[3 * N + i];

    double v = (double)N * (ss_s + ss_t) - 2.0 * rs_s * rs_t;
    v = wave_reduce_add(v);

    __shared__ double sm[8];
    const int wave = i >> 6;
    const int lane = i & 63;
    if (lane == 0) sm[wave] = v;
    __syncthreads();

    if (i == 0) {
        double total = 0.0;
        #pragma unroll
        for (int w = 0; w < 8; ++w) total += sm[w];
        out[0] = (float)(total / ((double)N * (double)N));
    }
}

extern "C" void kernel_launch(void* const* d_in, const int* in_sizes, int n_in,
                              void* d_out, int out_size, void* d_ws, size_t ws_size,
                              hipStream_t stream) {
    const float* src = (const float*)d_in[0];
    const float* tgt = (const float*)d_in[1];
    float* out = (float*)d_out;

    double* rs = (double*)d_ws;       // [4][512]
    double* ss = rs + 4 * N;          // [4][512]

    gw_dist    <<<dim3(256), dim3(512), 0, stream>>>(src, tgt, rs, ss);
    gw_finalize<<<dim3(1),   dim3(512), 0, stream>>>(rs, ss, out);
}

// Round 11
// 22.412 us; speedup vs baseline: 1.0047x; 1.0047x over previous
//
#include <hip/hip_runtime.h>

#define N 512
#define D 128

// ws layout (doubles): rs[2jh][2m][512] (8 KB) | ss[2jh][2m][512] (8 KB)
// Plain stores only — no atomics, no counters (R8's proven structure).

__device__ __forceinline__ double wave_reduce_add(double v) {
    #pragma unroll
    for (int off = 32; off > 0; off >>= 1)
        v += __shfl_down(v, off, 64);
    return v;
}

// K1: 256 blocks x 512 threads. b -> m = b>>7, ioct = (b&127)>>1, jh = b&1.
// Block computes dist(i, j) for i in [8*ioct, +8), j in [256*jh, +256).
// One LDS stage (128 KB transposed+swizzled tile), one barrier, then an
// LDS-read-minimal compute: thread = (j, d-half), 8 i-rows -> 8 FMAs per
// LDS float, 64 ds_read_b32 per thread.
// R9 bug fixed: stage loop now covers all 8192 float4 (16 passes, not 8).
__global__ __launch_bounds__(512) void gw_dist(
    const float* __restrict__ src, const float* __restrict__ tgt,
    double* __restrict__ rs, double* __restrict__ ss)
{
    __shared__ float  tile[D * 256];    // 128 KB: tile[d*256 + (j ^ ((d>>2)&31))]
    __shared__ float  part[256][9];     // hi-d-half partials (padded: no conflicts)
    __shared__ double red[8][16];       // [wave][quantity]

    const int b    = blockIdx.x;
    const int m    = b >> 7;
    const int ioct = (b & 127) >> 1;
    const int jh   = b & 1;
    const int t    = threadIdx.x;
    const int jl   = t & 255;           // local j
    const int dh   = t >> 8;            // d-half: 0 -> [0,64), 1 -> [64,128)
    const int i0   = ioct * 8;
    const int j0   = jh * 256;

    const float*  X  = m ? tgt : src;
    const float4* X4 = reinterpret_cast<const float4*>(X + j0 * D);

    // ---- stage: 256 j-rows x 32 float4 = 8192 float4, coalesced reads;
    // transposed swizzled writes X[j0+jr][4s+k] -> tile[(4s+k)*256 + (jr^s)].
    // Write banks per 32-lane group: jr uniform, s=lane -> (jr^s) permutation
    // of 0..31 -> conflict-free.
    #pragma unroll
    for (int p = 0; p < 16; ++p) {
        int f  = t + p * 512;           // flat float4 index 0..8191
        int jr = f >> 5;                // 0..255
        int s  = f & 31;
        float4 v = X4[f];
        int col = jr ^ s;
        // col = (jr & ~31) | ((jr ^ s) & 31): jr^s only permutes low 5 bits
        col = (jr & ~31) | ((jr ^ s) & 31);
        tile[(4 * s + 0) * 256 + col] = v.x;
        tile[(4 * s + 1) * 256 + col] = v.y;
        tile[(4 * s + 2) * 256 + col] = v.z;
        tile[(4 * s + 3) * 256 + col] = v.w;
    }
    __syncthreads();

    // ---- compute: 64 dims for this thread's (j, d-half), against 8 i-rows
    // (wave-uniform addresses -> scalar loads from K$).
    const int dbase = dh * 64;
    float a0 = 0.f, a1 = 0.f, a2 = 0.f, a3 = 0.f;
    float a4 = 0.f, a5 = 0.f, a6 = 0.f, a7 = 0.f;
    const float* r0 = X + (i0 + 0) * D + dbase;
    const float* r1 = X + (i0 + 1) * D + dbase;
    const float* r2 = X + (i0 + 2) * D + dbase;
    const float* r3 = X + (i0 + 3) * D + dbase;
    const float* r4 = X + (i0 + 4) * D + dbase;
    const float* r5 = X + (i0 + 5) * D + dbase;
    const float* r6 = X + (i0 + 6) * D + dbase;
    const float* r7 = X + (i0 + 7) * D + dbase;

    #pragma unroll 4
    for (int dd = 0; dd < 64; ++dd) {
        int d = dbase + dd;
        int col = (jl & ~31) | ((jl ^ (d >> 2)) & 31);
        float v = tile[d * 256 + col];  // 2 lanes/bank: free
        float e;
        e = r0[dd] - v; a0 += e * e;
        e = r1[dd] - v; a1 += e * e;
        e = r2[dd] - v; a2 += e * e;
        e = r3[dd] - v; a3 += e * e;
        e = r4[dd] - v; a4 += e * e;
        e = r5[dd] - v; a5 += e * e;
        e = r6[dd] - v; a6 += e * e;
        e = r7[dd] - v; a7 += e * e;
    }

    // ---- recombine d-halves per (i, j) BEFORE squaring ----
    if (dh == 1) {
        part[jl][0] = a0; part[jl][1] = a1; part[jl][2] = a2; part[jl][3] = a3;
        part[jl][4] = a4; part[jl][5] = a5; part[jl][6] = a6; part[jl][7] = a7;
    }
    __syncthreads();

    double q[16];
    if (dh == 0) {
        float c;
        c = a0 + part[jl][0]; q[0] = (double)c; q[8]  = (double)c * (double)c;
        c = a1 + part[jl][1]; q[1] = (double)c; q[9]  = (double)c * (double)c;
        c = a2 + part[jl][2]; q[2] = (double)c; q[10] = (double)c * (double)c;
        c = a3 + part[jl][3]; q[3] = (double)c; q[11] = (double)c * (double)c;
        c = a4 + part[jl][4]; q[4] = (double)c; q[12] = (double)c * (double)c;
        c = a5 + part[jl][5]; q[5] = (double)c; q[13] = (double)c * (double)c;
        c = a6 + part[jl][6]; q[6] = (double)c; q[14] = (double)c * (double)c;
        c = a7 + part[jl][7]; q[7] = (double)c; q[15] = (double)c * (double)c;
    } else {
        #pragma unroll
        for (int k = 0; k < 16; ++k) q[k] = 0.0;
    }

    // ---- block reduce 16 doubles (rs x8 rows, ss x8 rows) ----
    const int wave = t >> 6;
    const int lane = t & 63;
    #pragma unroll
    for (int k = 0; k < 16; ++k) {
        double v = wave_reduce_add(q[k]);
        if (lane == 0) red[wave][k] = v;
    }
    __syncthreads();

    if (t == 0) {
        const int base = ((jh << 1) | m) * N + i0;   // [jh][m][i] partials
        #pragma unroll
        for (int k = 0; k < 8; ++k) {
            double rsk = 0.0, ssk = 0.0;
            #pragma unroll
            for (int w = 0; w < 8; ++w) { rsk += red[w][k]; ssk += red[w][k + 8]; }
            rs[base + k] = rsk;   // plain stores; visible to K2 at kernel boundary
            ss[base + k] = ssk;
        }
    }
}

// K2: single block combines the 2 j-half partials and finalizes.
__global__ __launch_bounds__(512) void gw_finalize(
    const double* __restrict__ rs, const double* __restrict__ ss,
    float* __restrict__ out)
{
    const int i = threadIdx.x;

    // index ((jh<<1)|m)*N + i
    const double rs_s = rs[0 * N + i] + rs[2 * N + i];
    const double rs_t = rs[1 * N + i] + rs[3 * N + i];
    const double ss_s = ss[0 * N + i] + ss[2 * N + i];
    const double ss_t = ss[1 * N + i] + ss[3 * N + i];

    double v = (double)N * (ss_s + ss_t) - 2.0 * rs_s * rs_t;
    v = wave_reduce_add(v);

    __shared__ double sm[8];
    const int wave = i >> 6;
    const int lane = i & 63;
    if (lane == 0) sm[wave] = v;
    __syncthreads();

    if (i == 0) {
        double total = 0.0;
        #pragma unroll
        for (int w = 0; w < 8; ++w) total += sm[w];
        out[0] = (float)(total / ((double)N * (double)N));
    }
}

extern "C" void kernel_launch(void* const* d_in, const int* in_sizes, int n_in,
                              void* d_out, int out_size, void* d_ws, size_t ws_size,
                              hipStream_t stream) {
    const float* src = (const float*)d_in[0];
    const float* tgt = (const float*)d_in[1];
    float* out = (float*)d_out;

    double* rs = (double*)d_ws;       // [4][512]
    double* ss = rs + 4 * N;          // [4][512]

    gw_dist    <<<dim3(256), dim3(512), 0, stream>>>(src, tgt, rs, ss);
    gw_finalize<<<dim3(1),   dim3(512), 0, stream>>>(rs, ss, out);
}

// Round 12
// 16.194 us; speedup vs baseline: 1.3904x; 1.3840x over previous
//
#include <hip/hip_runtime.h>

#define N 512
#define D 128

// ws layout (doubles): rs[2jh*2m][512] (16 KB) | ss[2jh*2m][512] (16 KB)
// Plain stores only — no atomics, no counters (R8's proven structure).

__device__ __forceinline__ float wave_reduce_add_f32(float v) {
    #pragma unroll
    for (int off = 32; off > 0; off >>= 1)
        v += __shfl_down(v, off, 64);
    return v;
}

// K1: 512 blocks x 256 threads. b -> m = b>>8, iq = (b>>1)&127, jh = b&1.
// Block computes dist(i, j) for i in [4*iq, +4), j in [256*jh, +256).
// R8's proven chunked self-staging (4 chunks of 32 dims, padded transpose
// tile), but: tile is 32.9 KB -> 2 blocks/CU (cross-block latency hiding),
// and the reduction tail runs in f32 (half the shuffle cost), with the
// cross-wave combine in double. Thread = local j; owns full f32 distances.
__global__ __launch_bounds__(256) void gw_dist(
    const float* __restrict__ src, const float* __restrict__ tgt,
    double* __restrict__ rs, double* __restrict__ ss)
{
    __shared__ float tile[32 * 257];   // 32.9 KB: one 32-d chunk, transposed+padded
    __shared__ float redf[4][8];       // [wave][quantity] f32 per-wave sums

    const int b  = blockIdx.x;
    const int m  = b >> 8;             // matrix
    const int iq = (b >> 1) & 127;     // i-quad
    const int jh = b & 1;              // j-half
    const int t  = threadIdx.x;        // local j (0..255)
    const int i0 = iq * 4;
    const int j0 = jh * 256;

    const float*  X  = m ? tgt : src;
    const float4* X4 = reinterpret_cast<const float4*>(X + j0 * D);

    const int jhome = t >> 3;          // 0..31: staging row covered per pass
    const int d4    = t & 7;           // float4 slot within the 32-d chunk

    float a0 = 0.f, a1 = 0.f, a2 = 0.f, a3 = 0.f;

    for (int c = 0; c < 4; ++c) {      // d-chunk: dims [c*32, c*32+32)
        if (c) __syncthreads();        // protect tile before overwrite

        // ---- stage: 8 passes cover 256 j-rows; 8 lanes/row -> each wave
        // reads full 128B lines (ideal coalescing) ----
        #pragma unroll
        for (int p = 0; p < 8; ++p) {
            int jr = p * 32 + jhome;
            float4 v = X4[jr * 32 + c * 8 + d4];
            tile[(d4 * 4 + 0) * 257 + jr] = v.x;
            tile[(d4 * 4 + 1) * 257 + jr] = v.y;
            tile[(d4 * 4 + 2) * 257 + jr] = v.z;
            tile[(d4 * 4 + 3) * 257 + jr] = v.w;
        }
        __syncthreads();

        // ---- compute 32 dims for this thread's j, against 4 i-rows
        // (wave-uniform addresses -> scalar loads from K$) ----
        const int dbase = c * 32;
        const float* r0 = X + (i0 + 0) * D + dbase;
        const float* r1 = X + (i0 + 1) * D + dbase;
        const float* r2 = X + (i0 + 2) * D + dbase;
        const float* r3 = X + (i0 + 3) * D + dbase;

        #pragma unroll
        for (int dd = 0; dd < 32; ++dd) {
            float v = tile[dd * 257 + t];   // lane stride 1: 2 lanes/bank, free
            float e;
            e = r0[dd] - v; a0 += e * e;
            e = r1[dd] - v; a1 += e * e;
            e = r2[dd] - v; a2 += e * e;
            e = r3[dd] - v; a3 += e * e;
        }
    }

    // a* are the exact f32 pair-costs (identical math to all validated
    // rounds). Wave-level j-sums in f32 (error ~1e-7 rel, budget 2.4e4);
    // cross-wave combine in double.
    float qv[8];
    qv[0] = a0; qv[1] = a1; qv[2] = a2; qv[3] = a3;
    qv[4] = a0 * a0; qv[5] = a1 * a1; qv[6] = a2 * a2; qv[7] = a3 * a3;

    const int wave = t >> 6;
    const int lane = t & 63;
    #pragma unroll
    for (int k = 0; k < 8; ++k) {
        float v = wave_reduce_add_f32(qv[k]);
        if (lane == 0) redf[wave][k] = v;
    }
    __syncthreads();

    if (t == 0) {
        const int base = ((jh << 1) | m) * N + i0;   // [jh][m][i] partials
        #pragma unroll
        for (int k = 0; k < 4; ++k) {
            double rsk = (double)redf[0][k]     + (double)redf[1][k]
                       + (double)redf[2][k]     + (double)redf[3][k];
            double ssk = (double)redf[0][k + 4] + (double)redf[1][k + 4]
                       + (double)redf[2][k + 4] + (double)redf[3][k + 4];
            rs[base + k] = rsk;   // plain stores; visible to K2 at kernel boundary
            ss[base + k] = ssk;
        }
    }
}

// K2: single block combines the 2 j-half partials and finalizes (validated R11).
__global__ __launch_bounds__(512) void gw_finalize(
    const double* __restrict__ rs, const double* __restrict__ ss,
    float* __restrict__ out)
{
    const int i = threadIdx.x;

    // index ((jh<<1)|m)*N + i
    const double rs_s = rs[0 * N + i] + rs[2 * N + i];
    const double rs_t = rs[1 * N + i] + rs[3 * N + i];
    const double ss_s = ss[0 * N + i] + ss[2 * N + i];
    const double ss_t = ss[1 * N + i] + ss[3 * N + i];

    double v = (double)N * (ss_s + ss_t) - 2.0 * rs_s * rs_t;
    #pragma unroll
    for (int off = 32; off > 0; off >>= 1)
        v += __shfl_down(v, off, 64);

    __shared__ double sm[8];
    const int wave = i >> 6;
    const int lane = i & 63;
    if (lane == 0) sm[wave] = v;
    __syncthreads();

    if (i == 0) {
        double total = 0.0;
        #pragma unroll
        for (int w = 0; w < 8; ++w) total += sm[w];
        out[0] = (float)(total / ((double)N * (double)N));
    }
}

extern "C" void kernel_launch(void* const* d_in, const int* in_sizes, int n_in,
                              void* d_out, int out_size, void* d_ws, size_t ws_size,
                              hipStream_t stream) {
    const float* src = (const float*)d_in[0];
    const float* tgt = (const float*)d_in[1];
    float* out = (float*)d_out;

    double* rs = (double*)d_ws;       // [4][512]
    double* ss = rs + 4 * N;          // [4][512]

    gw_dist    <<<dim3(512), dim3(256), 0, stream>>>(src, tgt, rs, ss);
    gw_finalize<<<dim3(1),   dim3(512), 0, stream>>>(rs, ss, out);
}